// Round 7
// baseline (125.038 us; speedup 1.0000x reference)
//
#include <hip/hip_runtime.h>
#include <hip/hip_bf16.h>
#include <hip/hip_fp16.h>

#define DIM 256
#define NP 2048
#define NH 8
#define BATCH 2
#define DH 32

typedef __attribute__((ext_vector_type(8))) short bshort8;
typedef __attribute__((ext_vector_type(4))) short bshort4;
typedef __attribute__((ext_vector_type(4))) float f32x4;

#define LOG2E 1.44269504f
#define LN2F 0.6931472f
// (Dh^-0.5) * log2(e), folded into WT rows 0..255 (W_q) at prep time
#define QSCALE (0.17677669529663687f * LOG2E)

union U16B { uint4 u; bshort8 s8; bshort4 s4x[2]; __hip_bfloat16 h[8]; };
union U8B  { uint2 u; bshort4 s4; __hip_bfloat16 h[4]; };

__device__ __forceinline__ float fexp2(float x) { return __builtin_amdgcn_exp2f(x); }
// pack two fp32 -> two bf16 (truncation) in one v_perm
__device__ __forceinline__ unsigned packbf(float hi, float lo) {
    return __builtin_amdgcn_perm(__float_as_uint(hi), __float_as_uint(lo), 0x07060302u);
}
// async global->LDS, 16B per lane. LDS dest = wave-uniform base + lane*16.
__device__ __forceinline__ void gl16(const void* g, void* l) {
    __builtin_amdgcn_global_load_lds(
        (const __attribute__((address_space(1))) void*)g,
        (__attribute__((address_space(3))) void*)l, 16, 0, 0);
}
// LDS tile addressing: 64 rows x 256 elems, XOR-swizzled 16B granules.
__device__ __forceinline__ int lds_addr(int row, int colg) {
    return row * 256 + (((colg ^ (row & 7)) & 31) << 3);
}

// ============ kernel 0: prep — W transpose -> bf16 WT[1024][256]; x -> bf16 ==
__global__ __launch_bounds__(256) void prep_kernel(
    const float* __restrict__ Wqk,
    const float* __restrict__ Wv,
    const float* __restrict__ Wproj,
    const float* __restrict__ x,
    __hip_bfloat16* __restrict__ WT,
    __hip_bfloat16* __restrict__ xb) {
    const int t = threadIdx.x;
    const int blk = blockIdx.x;
    if (blk >= 64) {
        const int base = (blk - 64) * 256 + t;
#pragma unroll
        for (int i = 0; i < 16; i++) {
            const int idx = base + i * 16384;
            float4 f = *(const float4*)(x + (size_t)idx * 4);
            U8B a;
            a.h[0] = __float2bfloat16(f.x); a.h[1] = __float2bfloat16(f.y);
            a.h[2] = __float2bfloat16(f.z); a.h[3] = __float2bfloat16(f.w);
            *(uint2*)(xb + (size_t)idx * 4) = a.u;
        }
        return;
    }
    __shared__ float ts[64][65];
    const int ct = blk >> 2, k0 = (blk & 3) * 64;
    const int c0 = ct * 64;
    const float* src; int ldw, cs0; float scl = 1.0f;
    if (ct < 8)       { src = Wqk;   ldw = 512; cs0 = c0;      if (ct < 4) scl = QSCALE; }
    else if (ct < 12) { src = Wv;    ldw = 256; cs0 = c0 - 512; }
    else              { src = Wproj; ldw = 256; cs0 = c0 - 768; }
    const int cc = t & 63, tq = t >> 6;
#pragma unroll
    for (int j = 0; j < 16; j++) {
        int kk = tq * 16 + j;
        ts[kk][cc] = src[(size_t)(k0 + kk) * ldw + cs0 + cc];
    }
    __syncthreads();
    const int kk2 = t & 63;
#pragma unroll
    for (int j = 0; j < 16; j++) {
        int cc2 = tq * 16 + j;
        WT[(size_t)(c0 + cc2) * 256 + k0 + kk2] = __float2bfloat16(ts[kk2][cc2] * scl);
    }
}

// ============ kernel 1: QKV projection — global_load_lds staged MFMA GEMM ===
__global__ __launch_bounds__(256) void qkv_mfma(
    const __hip_bfloat16* __restrict__ xb,
    const __hip_bfloat16* __restrict__ WT,
    __hip_bfloat16* __restrict__ qT,
    __hip_bfloat16* __restrict__ k,
    __hip_bfloat16* __restrict__ vT) {
    __shared__ __align__(16) __hip_bfloat16 As[64 * 256];
    __shared__ __align__(16) __hip_bfloat16 Bs[64 * 256];
    const int t = threadIdx.x, lane = t & 63, wvid = t >> 6;
    const int l15 = lane & 15, l4 = lane >> 4;
    const int m0 = blockIdx.x * 64;
    const int nb0 = blockIdx.y * 64;
    const int nc = nb0 + wvid * 16 + l15;
    const int lrow = lane >> 5, lcg = lane & 31;

#pragma unroll
    for (int j = 0; j < 8; j++) {
        const int r0 = j * 8 + wvid * 2;
        const int row = r0 + lrow;
        const int cgs = (lcg ^ (row & 7)) & 31;
        gl16(xb + (((size_t)(m0 + row)) << 8) + cgs * 8, (char*)As + r0 * 512);
        gl16(WT + (((size_t)(nb0 + row)) << 8) + cgs * 8, (char*)Bs + r0 * 512);
    }
    __syncthreads();

    f32x4 acc[4] = {{0.f,0.f,0.f,0.f},{0.f,0.f,0.f,0.f},{0.f,0.f,0.f,0.f},{0.f,0.f,0.f,0.f}};
#pragma unroll
    for (int kk = 0; kk < 8; kk++) {
        const int colg = kk * 4 + l4;
        U16B bw; bw.u = *(const uint4*)&Bs[lds_addr(wvid * 16 + l15, colg)];
#pragma unroll
        for (int mt = 0; mt < 4; mt++) {
            U16B ax; ax.u = *(const uint4*)&As[lds_addr(mt * 16 + l15, colg)];
            acc[mt] = __builtin_amdgcn_mfma_f32_16x16x32_bf16(ax.s8, bw.s8, acc[mt], 0, 0, 0);
        }
    }

    if (nb0 < 256) {             // qT[(b*256+c)][token], 8B stores (QSCALE in WT)
        const int b = m0 >> 11;
#pragma unroll
        for (int mt = 0; mt < 4; mt++) {
            int tokn = (m0 & (NP - 1)) + mt * 16 + l4 * 4;
            U8B vv;
#pragma unroll
            for (int r = 0; r < 4; r++) vv.h[r] = __float2bfloat16(acc[mt][r]);
            *(uint2*)(qT + (size_t)(b * 256 + nc) * NP + tokn) = vv.u;
        }
    } else if (nb0 < 512) {      // k[bh][n][d] (row layout needed by attn staging)
        const int c = nc - 256, h = c >> 5, d = c & 31;
#pragma unroll
        for (int mt = 0; mt < 4; mt++)
#pragma unroll
            for (int r = 0; r < 4; r++) {
                int tok = m0 + mt * 16 + l4 * 4 + r;
                int b = tok >> 11, n = tok & (NP - 1);
                k[((size_t)(b * NH + h) * NP + n) * DH + d] = __float2bfloat16(acc[mt][r]);
            }
    } else {                     // vT[(b*256+c)][token], 8B stores
        const int c = nc - 512;
        const int b = m0 >> 11;
#pragma unroll
        for (int mt = 0; mt < 4; mt++) {
            int tokn = (m0 & (NP - 1)) + mt * 16 + l4 * 4;
            U8B vv;
#pragma unroll
            for (int r = 0; r < 4; r++) vv.h[r] = __float2bfloat16(acc[mt][r]);
            *(uint2*)(vT + (size_t)(b * 256 + c) * NP + tokn) = vv.u;
        }
    }
}

// ============ kernel 2: attention + fused positional scan ===================
// grid 512 = bh(16) x qb(32). Blocks 0..63 additionally run the positional
// geometric scan FIRST (producer), then signal sem; all blocks consume NF/NB
// in the epilogue after an acquire spin. All 512 blocks co-resident
// (LDS 47.4KB -> 3/CU cap by LDS, 2/CU by VGPR<=128 -> 512 resident).
__global__ __launch_bounds__(512, 4) void attn_kernel(
    const __hip_bfloat16* __restrict__ qg,   // qT[bh*32+d][n]
    const __hip_bfloat16* __restrict__ kg,
    const __hip_bfloat16* __restrict__ vTg,
    const float* __restrict__ Wpos,
    const float* __restrict__ gating,
    __half* __restrict__ NF,      // [16][2048][32] fwd scan  (shift pmF)
    __half* __restrict__ NB,      // [16][2048][32] bwd scan  (shift pmB, no diag)
    __hip_bfloat16* __restrict__ ao,
    unsigned* __restrict__ sem) {
    __shared__ __align__(16) __hip_bfloat16 Kt[2][2][64][40];  // [kh][buf][key][dh pad40]
    __shared__ __align__(16) __hip_bfloat16 Vt[2][2][32][72];  // [kh][buf][d][key perm pad72]
    __shared__ float cmb[4][32][16];   // [qt][d][q] partials; scan scratch early
    __shared__ float cls[4][16];

    const int t = threadIdx.x;
    const int bid = blockIdx.x;

    // ---------------- producer: positional scan (blocks 0..63) -------------
    // bid -> sbh(16) x dir(2) x chgrp(2); threads: seg = t>>4 (32 x 64 tokens),
    // ch16 = t&15. Phase A keeps 64 partials in registers; phase C is
    // independent (out[i] = S[i] + Cin*mr^(i+1)) — single pass over V.
    if (bid < 64) {
        float* scanL = &cmb[0][0][0];          // [16][33] carry-outs
        float* scanC = scanL + 544;            // [16][33] carry-ins
        const int sbh = bid >> 2, dir = (bid >> 1) & 1, cg = bid & 1;
        const int sh = sbh & (NH - 1), sb = sbh >> 3;
        const int seg = t >> 4, ch16 = t & 15, sch = cg * 16 + ch16;
        const float sw0 = Wpos[sh] * LOG2E, sw1 = Wpos[NH + sh] * LOG2E;
        const float rate = dir ? (sw1 - sw0) : (sw0 + sw1);
        const float mr = fexp2(fminf(rate, 0.f));     // homogeneous mult <= 1
        const float mrate = fmaxf(rate, 0.f);
        const int n0 = seg * 64;
        const float dist0 = dir ? (float)(1984 - n0) : (float)n0;
        float sclc = fexp2(-mrate * dist0);
        const float sd8 = fexp2(-mrate * 8.f);
        float sdp[8], mrp[9];
#pragma unroll
        for (int j = 0; j < 8; j++) sdp[j] = fexp2(-mrate * (float)j);
        mrp[0] = 1.f;
#pragma unroll
        for (int j = 1; j < 9; j++) mrp[j] = mrp[j - 1] * mr;
        const float mr8 = mrp[8];
        const __hip_bfloat16* vrow = vTg + ((size_t)(sb * 256 + sh * 32 + sch)) * NP;

        float S[64];
        float F = 0.f;
#pragma unroll
        for (int c = 0; c < 8; c++) {
            U16B vv;
            vv.u = *(const uint4*)(vrow + (dir ? (n0 + 56 - c * 8) : (n0 + c * 8)));
#pragma unroll
            for (int j = 0; j < 8; j++) {
                float V = __bfloat162float(vv.h[dir ? 7 - j : j]);
                float inp = sclc * (sdp[j] * V);
                float Fp = F;
                F = fmaf(mr, F, inp);
                S[c * 8 + j] = dir ? (mr * Fp) : F;   // bwd excludes diagonal
            }
            sclc *= sd8;
        }
        scanL[ch16 * 33 + seg] = F;
        __syncthreads();
        if (t < 16) {
            const float A64 = fexp2(fminf(rate, 0.f) * 64.f);
            float C = 0.f;
            for (int idx = 0; idx < 32; ++idx) {
                const int s = dir ? (31 - idx) : idx;
                scanC[t * 33 + s] = C;
                C = fmaf(A64, C, scanL[t * 33 + s]);
            }
        }
        __syncthreads();
        {
            const float Cin = scanC[ch16 * 33 + seg];
            __half* nout = dir ? NB : NF;
            float cm = Cin;
#pragma unroll
            for (int c = 0; c < 8; c++) {
#pragma unroll
                for (int j = 0; j < 8; j++) {
                    const int i = c * 8 + j;
                    float outv = fmaf(cm, mrp[j + 1], S[i]);
                    const int ni = dir ? (n0 + 63 - i) : (n0 + i);
                    nout[((size_t)sbh * NP + ni) * 32 + sch] = __float2half(outv);
                }
                cm *= mr8;
            }
        }
        __syncthreads();
        if (t == 0) {
            __threadfence();   // release producer writes
            __hip_atomic_fetch_add(sem, 1u, __ATOMIC_RELEASE, __HIP_MEMORY_SCOPE_AGENT);
        }
        __syncthreads();
    }

    // ---------------- content attention (all blocks) ------------------------
    const int lane = t & 63, wvid = t >> 6;
    const int l15 = lane & 15, l4 = lane >> 4;
    const int qt = wvid & 3, kh = wvid >> 2;
    const int bh = bid >> 5, qb = bid & 31;
    const int h = bh & (NH - 1), b = bh >> 3;
    const int q0 = qb * 64 + qt * 16;
    const int myq = q0 + l15;

    const int st_ = t & 255;
    const int kstart = kh * 1024;
    const __hip_bfloat16* kptr = kg + (size_t)bh * NP * DH + (size_t)(kstart + (st_ >> 2)) * DH + (st_ & 3) * 8;
    const __hip_bfloat16* vptr = vTg + ((size_t)bh * DH + (st_ >> 3)) * NP + kstart + (st_ & 7) * 8;

    // permuted V staging addresses (c = s*8+e -> c' = l4(c)*16 + kt(c)*4 + j(c))
    const int vd = st_ >> 3, vs = st_ & 7;
    const int vc0 = ((2 * vs) & 3) * 16 + (vs >> 1) * 4;
    const int vc1 = ((2 * vs + 1) & 3) * 16 + (vs >> 1) * 4;

    uint4 kreg = *(const uint4*)kptr;
    uint4 vreg = *(const uint4*)vptr;
    *(uint4*)&Kt[kh][0][st_ >> 2][(st_ & 3) * 8] = kreg;
    *(uint2*)&Vt[kh][0][vd][vc0] = make_uint2(vreg.x, vreg.y);
    *(uint2*)&Vt[kh][0][vd][vc1] = make_uint2(vreg.z, vreg.w);

    const float w0 = Wpos[h] * LOG2E;
    const float w1 = Wpos[NH + h] * LOG2E;
    const float g = 1.0f / (1.0f + __expf(-gating[h]));
    const float nf = (float)myq;

    U16B qv;
#pragma unroll
    for (int j = 0; j < 8; j++)
        qv.h[j] = qg[((size_t)bh * DH + l4 * 8 + j) * NP + myq];

    __syncthreads();

    f32x4 os0 = {0.f,0.f,0.f,0.f}, os1 = {0.f,0.f,0.f,0.f};
    float ls = 0.f;

    for (int it = 0; it < 16; ++it) {
        const int cur = it & 1, nxt = cur ^ 1;

        if (it < 15) {
            kreg = *(const uint4*)(kptr + (size_t)(it + 1) * 64 * DH);
            vreg = *(const uint4*)(vptr + (it + 1) * 64);
        }

        f32x4 st4[4];
#pragma unroll
        for (int kt = 0; kt < 4; kt++) {
            U16B kf; kf.u = *(const uint4*)&Kt[kh][cur][kt * 16 + l15][l4 * 8];
            st4[kt] = __builtin_amdgcn_mfma_f32_16x16x32_bf16(
                kf.s8, qv.s8, (f32x4){0.f,0.f,0.f,0.f}, 0, 0, 0);
        }

        // V fragments: 4x b128 reads thanks to column permutation
        U16B va0, va1, vb0, vb1;
        {
            const __hip_bfloat16* v0 = &Vt[kh][cur][l15][l4 * 16];
            const __hip_bfloat16* v1 = &Vt[kh][cur][16 + l15][l4 * 16];
            va0.u = *(const uint4*)v0;
            va1.u = *(const uint4*)(v0 + 8);
            vb0.u = *(const uint4*)v1;
            vb1.u = *(const uint4*)(v1 + 8);
        }

#pragma unroll
        for (int kt = 0; kt < 4; kt++) {
            const bshort4 fa = (kt < 2) ? va0.s4x[kt & 1] : va1.s4x[kt & 1];
            const bshort4 fb = (kt < 2) ? vb0.s4x[kt & 1] : vb1.s4x[kt & 1];
            float es0 = fexp2(st4[kt][0]), es1 = fexp2(st4[kt][1]);
            float es2 = fexp2(st4[kt][2]), es3 = fexp2(st4[kt][3]);
            ls += (es0 + es1) + (es2 + es3);
            U8B pc;
            pc.u.x = packbf(es1, es0); pc.u.y = packbf(es3, es2);
            os0 = __builtin_amdgcn_mfma_f32_16x16x16bf16_1k(fa, pc.s4, os0, 0, 0, 0);
            os1 = __builtin_amdgcn_mfma_f32_16x16x16bf16_1k(fb, pc.s4, os1, 0, 0, 0);
        }

        if (it < 15) {
            *(uint4*)&Kt[kh][nxt][st_ >> 2][(st_ & 3) * 8] = kreg;
            *(uint2*)&Vt[kh][nxt][vd][vc0] = make_uint2(vreg.x, vreg.y);
            *(uint2*)&Vt[kh][nxt][vd][vc1] = make_uint2(vreg.z, vreg.w);
        }
        __syncthreads();
    }

    ls += __shfl_xor(ls, 16, 64); ls += __shfl_xor(ls, 32, 64);

    if (kh == 1) {
#pragma unroll
        for (int r = 0; r < 4; r++) {
            cmb[qt][l4 * 4 + r][l15]      = os0[r];
            cmb[qt][16 + l4 * 4 + r][l15] = os1[r];
        }
        if (l4 == 0) cls[qt][l15] = ls;
    }
    // consumer wait: producers (blocks 0..63) must have published NF/NB.
    if (t == 0) {
        while (__hip_atomic_load(sem, __ATOMIC_ACQUIRE, __HIP_MEMORY_SCOPE_AGENT) < 64u)
            __builtin_amdgcn_s_sleep(2);
        __threadfence();   // acquire: invalidate caches before NF/NB reads
    }
    __syncthreads();
    if (kh == 0) {
        ls += cls[qt][l15];
        const float cs = (1.0f - g) / ls;
        // recombine the two shifted positional halves at the common row shift
        const float a2 = w0 + w1, b2 = w1 - w0;
        const float pmF = fmaxf(0.f, a2 * nf);
        const float pmB = fmaxf(0.f, b2 * (2047.f - nf));
        const float pm  = fmaxf(pmF, pmB);
        const float eF = fexp2(pmF - pm);
        const float eB = fexp2(pmB - pm);
        // closed-form shifted geometric denominators (stable via expm1):
        // lpF = sum_{e=0..n} 2^(-|a2| e), lpB = (b2>0 ? 1 : 2^-|b2|) * sum_{f=0..M-1} 2^(-|b2| f)
        const float aa = fabsf(a2), ab = fabsf(b2);
        const float Mf = 2047.f - nf;
        const float lpFv = (aa > 1e-9f)
            ? expm1f(-LN2F * aa * (nf + 1.f)) / expm1f(-LN2F * aa)
            : (nf + 1.f);
        float lpBv;
        if (ab > 1e-9f) {
            const float E = expm1f(-LN2F * ab * Mf) / expm1f(-LN2F * ab);
            lpBv = (b2 > 0.f) ? E : fexp2(-ab) * E;
        } else lpBv = Mf;
        const float lpv = eF * lpFv + eB * lpBv;
        const float cp = g / lpv;
        const size_t lpi = (size_t)bh * NP + myq;
        const __half* nfp = NF + lpi * 32 + l4 * 4;
        const __half* nbp = NB + lpi * 32 + l4 * 4;
        const size_t orow = ((size_t)b * NP + myq) * DIM + h * DH;
        U8B o0, o1;
#pragma unroll
        for (int r = 0; r < 4; r++) {
            float p0 = eF * __half2float(nfp[r])      + eB * __half2float(nbp[r]);
            float p1 = eF * __half2float(nfp[16 + r]) + eB * __half2float(nbp[16 + r]);
            o0.h[r] = __float2bfloat16(cs * (os0[r] + cmb[qt][l4 * 4 + r][l15]) + cp * p0);
            o1.h[r] = __float2bfloat16(cs * (os1[r] + cmb[qt][16 + l4 * 4 + r][l15]) + cp * p1);
        }
        *(uint2*)(ao + orow + l4 * 4)      = o0.u;
        *(uint2*)(ao + orow + 16 + l4 * 4) = o1.u;
    }
}

// ============ kernel 3: output projection — global_load_lds staged GEMM =====
__global__ __launch_bounds__(256) void proj_mfma(
    const __hip_bfloat16* __restrict__ ao,
    const __hip_bfloat16* __restrict__ WT,
    const float* __restrict__ bias,
    float* __restrict__ out) {
    __shared__ __align__(16) __hip_bfloat16 As[64 * 256];
    __shared__ __align__(16) __hip_bfloat16 Bs[64 * 256];
    const int t = threadIdx.x, lane = t & 63, wvid = t >> 6;
    const int l15 = lane & 15, l4 = lane >> 4;
    const int m0 = blockIdx.x * 64;
    const int nb0 = blockIdx.y * 64;
    const int nc = nb0 + wvid * 16 + l15;
    const int lrow = lane >> 5, lcg = lane & 31;

#pragma unroll
    for (int j = 0; j < 8; j++) {
        const int r0 = j * 8 + wvid * 2;
        const int row = r0 + lrow;
        const int cgs = (lcg ^ (row & 7)) & 31;
        gl16(ao + (((size_t)(m0 + row)) << 8) + cgs * 8, (char*)As + r0 * 512);
        gl16(WT + (((size_t)(768 + nb0 + row)) << 8) + cgs * 8, (char*)Bs + r0 * 512);
    }
    __syncthreads();

    f32x4 acc[4] = {{0.f,0.f,0.f,0.f},{0.f,0.f,0.f,0.f},{0.f,0.f,0.f,0.f},{0.f,0.f,0.f,0.f}};
#pragma unroll
    for (int kk = 0; kk < 8; kk++) {
        const int colg = kk * 4 + l4;
        U16B bw; bw.u = *(const uint4*)&Bs[lds_addr(wvid * 16 + l15, colg)];
#pragma unroll
        for (int mt = 0; mt < 4; mt++) {
            U16B ax; ax.u = *(const uint4*)&As[lds_addr(mt * 16 + l15, colg)];
            acc[mt] = __builtin_amdgcn_mfma_f32_16x16x32_bf16(ax.s8, bw.s8, acc[mt], 0, 0, 0);
        }
    }

    const float bb = bias[nc];
#pragma unroll
    for (int mt = 0; mt < 4; mt++)
#pragma unroll
        for (int r = 0; r < 4; r++) {
            int tok = m0 + mt * 16 + l4 * 4 + r;
            out[(size_t)tok * 256 + nc] = acc[mt][r] + bb;
        }
}

extern "C" void kernel_launch(void* const* d_in, const int* in_sizes, int n_in,
                              void* d_out, int out_size, void* d_ws, size_t ws_size,
                              hipStream_t stream) {
    const float* x      = (const float*)d_in[0];
    const float* Wqk    = (const float*)d_in[1];
    const float* Wv     = (const float*)d_in[2];
    const float* Wproj  = (const float*)d_in[3];
    const float* bproj  = (const float*)d_in[4];
    const float* Wpos   = (const float*)d_in[5];
    const float* gating = (const float*)d_in[7];
    float* out = (float*)d_out;

    char* w = (char*)d_ws;
    __hip_bfloat16* WT = (__hip_bfloat16*)w;        // 0.5 MB
    __hip_bfloat16* qT = WT + 262144;               // 2 MB
    __hip_bfloat16* k  = qT + 1048576;              // 2 MB
    __hip_bfloat16* vT = k  + 1048576;              // 2 MB
    __hip_bfloat16* ao = vT + 1048576;              // 2 MB
    __hip_bfloat16* xb = ao + 1048576;              // 2 MB  (ends 11,010,048 B)
    __half* NF = (__half*)(w + 11010048);           // 2 MB
    __half* NB = (__half*)(w + 13107200);           // 2 MB
    unsigned* sem = (unsigned*)(w + (16u << 20));   // producer-done semaphore

    hipMemsetAsync(sem, 0, 64, stream);             // capture-legal async node

    prep_kernel<<<128, 256, 0, stream>>>(Wqk, Wv, Wproj, x, WT, xb);
    qkv_mfma<<<dim3(64, 12), 256, 0, stream>>>(xb, WT, qT, k, vT);
    attn_kernel<<<BATCH * NH * (NP / 64), 512, 0, stream>>>(qT, k, vT, Wpos, gating,
                                                            NF, NB, ao, sem);
    proj_mfma<<<dim3(64, 4), 256, 0, stream>>>(ao, WT, bproj, out);
}